// Round 3
// baseline (3742.439 us; speedup 1.0000x reference)
//
#include <hip/hip_runtime.h>

#define N_NODES 16384
#define E_EDGES 65536
#define HIDC 256
#define NM ((size_t)N_NODES * HIDC)   // 4194304 floats

__device__ __forceinline__ float gelu_f(float x) {
  // jax.nn.gelu (approximate=True)
  return 0.5f * x * (1.0f + tanhf(0.7978845608028654f * (x + 0.044715f * x * x * x)));
}

// ================= GEMM: C[16384x256] = act(A) @ W[256x256] + bias =================
// 128x128 block tile, 256 threads, 2x2 blocks of 4x4 per thread, reg-prefetch dbuf.
template<bool GELU_IN>
__global__ __launch_bounds__(256)
void gemm128(const float* __restrict__ A, const float* __restrict__ W,
             const float* __restrict__ bias, float* __restrict__ C) {
  __shared__ float As[32][132];   // As[k][m], padded stride (16B-aligned rows)
  __shared__ float Bs[32][128];   // Bs[k][n]
  const int tid = threadIdx.x;
  const int bn = blockIdx.x * 128;
  const int bm = blockIdx.y * 128;
  const int tx = tid & 15, ty = tid >> 4;
  float4 ra[4], rb[4];
  float acc[2][2][4][4] = {};

  auto loadA = [&](int k0) {
    #pragma unroll
    for (int i = 0; i < 4; i++) {
      int idx = tid + i * 256;
      int row = idx >> 3, kq = idx & 7;
      ra[i] = *(const float4*)&A[(size_t)(bm + row) * HIDC + k0 + kq * 4];
    }
  };
  auto loadB = [&](int k0) {
    #pragma unroll
    for (int i = 0; i < 4; i++) {
      int idx = tid + i * 256;
      int krow = idx >> 5, c4 = idx & 31;
      rb[i] = *(const float4*)&W[(size_t)(k0 + krow) * HIDC + bn + c4 * 4];
    }
  };

  loadA(0); loadB(0);
  #pragma unroll 1
  for (int t = 0; t < 8; t++) {
    __syncthreads();
    #pragma unroll
    for (int i = 0; i < 4; i++) {
      int idx = tid + i * 256;
      int row = idx >> 3, kq = idx & 7;
      float vx = ra[i].x, vy = ra[i].y, vz = ra[i].z, vw = ra[i].w;
      if (GELU_IN) { vx = gelu_f(vx); vy = gelu_f(vy); vz = gelu_f(vz); vw = gelu_f(vw); }
      As[kq * 4 + 0][row] = vx;
      As[kq * 4 + 1][row] = vy;
      As[kq * 4 + 2][row] = vz;
      As[kq * 4 + 3][row] = vw;
    }
    #pragma unroll
    for (int i = 0; i < 4; i++) {
      int idx = tid + i * 256;
      int krow = idx >> 5, c4 = idx & 31;
      *(float4*)&Bs[krow][c4 * 4] = rb[i];
    }
    __syncthreads();
    if (t < 7) { loadA((t + 1) * 32); loadB((t + 1) * 32); }
    #pragma unroll
    for (int kk = 0; kk < 32; kk++) {
      float4 a0 = *(const float4*)&As[kk][ty * 4];
      float4 a1 = *(const float4*)&As[kk][64 + ty * 4];
      float4 b0 = *(const float4*)&Bs[kk][tx * 4];
      float4 b1 = *(const float4*)&Bs[kk][64 + tx * 4];
      float av[2][4] = {{a0.x, a0.y, a0.z, a0.w}, {a1.x, a1.y, a1.z, a1.w}};
      float bv[2][4] = {{b0.x, b0.y, b0.z, b0.w}, {b1.x, b1.y, b1.z, b1.w}};
      #pragma unroll
      for (int im = 0; im < 2; im++)
        #pragma unroll
        for (int i = 0; i < 4; i++)
          #pragma unroll
          for (int jn = 0; jn < 2; jn++)
            #pragma unroll
            for (int j = 0; j < 4; j++)
              acc[im][jn][i][j] += av[im][i] * bv[jn][j];
    }
  }
  float4 bv0 = *(const float4*)&bias[bn + tx * 4];
  float4 bv1 = *(const float4*)&bias[bn + 64 + tx * 4];
  #pragma unroll
  for (int im = 0; im < 2; im++)
    #pragma unroll
    for (int i = 0; i < 4; i++) {
      size_t ro = (size_t)(bm + im * 64 + ty * 4 + i) * HIDC;
      float4 o0, o1;
      o0.x = acc[im][0][i][0] + bv0.x; o0.y = acc[im][0][i][1] + bv0.y;
      o0.z = acc[im][0][i][2] + bv0.z; o0.w = acc[im][0][i][3] + bv0.w;
      o1.x = acc[im][1][i][0] + bv1.x; o1.y = acc[im][1][i][1] + bv1.y;
      o1.z = acc[im][1][i][2] + bv1.z; o1.w = acc[im][1][i][3] + bv1.w;
      *(float4*)&C[ro + bn + tx * 4] = o0;
      *(float4*)&C[ro + bn + 64 + tx * 4] = o1;
    }
}

// ================= fused weight build: W' = Wsrc . blockdiag(A), b' = bsrc . blockdiag(A) ======
// grid (8 heads, 16 l*4+r, 2 K/V), block 256
__global__ __launch_bounds__(256)
void fuse_kernel(const float* __restrict__ Kw, const float* __restrict__ Kb,
                 const float* __restrict__ Vw, const float* __restrict__ Vb,
                 const float* __restrict__ Arel, const float* __restrict__ Mrel,
                 float* __restrict__ fw, float* __restrict__ fb) {
  const int h = blockIdx.x;
  const int lr = blockIdx.y;            // l*4 + r
  const int kv = blockIdx.z;
  const int l = lr >> 2, r = lr & 3;
  const int s = (r == 0) ? 1 : (r == 2) ? 2 : 0;   // REL src types {1,0,2,0}
  const float* Wsrc = (kv ? Vw : Kw) + (size_t)(l * 3 + s) * 65536;
  const float* bsrc = (kv ? Vb : Kb) + (size_t)(l * 3 + s) * 256;
  const float* A    = (kv ? Mrel : Arel) + (size_t)lr * 8192 + h * 1024;
  float* fwp = fw + (size_t)(lr * 2 + kv) * 65536;
  float* fbp = fb + (size_t)(lr * 2 + kv) * 256;
  __shared__ float Am[32][32];
  const int tid = threadIdx.x;
  #pragma unroll
  for (int i = 0; i < 4; i++) { int p = tid + i * 256; Am[p >> 5][p & 31] = A[p]; }
  __syncthreads();
  float w[32];
  #pragma unroll
  for (int d = 0; d < 32; d++) w[d] = Wsrc[(size_t)tid * 256 + h * 32 + d];
  #pragma unroll
  for (int e = 0; e < 32; e++) {
    float sacc = 0.0f;
    #pragma unroll
    for (int d = 0; d < 32; d++) sacc += w[d] * Am[d][e];
    fwp[(size_t)tid * 256 + h * 32 + e] = sacc;
  }
  if (tid < 32) {
    float sacc = 0.0f;
    #pragma unroll
    for (int d = 0; d < 32; d++) sacc += bsrc[h * 32 + d] * Am[d][tid];
    fbp[h * 32 + tid] = sacc;
  }
}

// ================= per-relation CSR build =================
__global__ __launch_bounds__(256)
void zero_cnt_kernel(int* __restrict__ cnt) {
  cnt[blockIdx.x * 256 + threadIdx.x] = 0;
}

__global__ __launch_bounds__(256)
void count_kernel(const int* __restrict__ e0, const int* __restrict__ e1,
                  const int* __restrict__ e2, const int* __restrict__ e3,
                  int* __restrict__ cnt) {
  int g = blockIdx.x * 256 + threadIdx.x;
  int r = g >> 16, e = g & 0xFFFF;
  const int* ei = (r == 0) ? e0 : (r == 1) ? e1 : (r == 2) ? e2 : e3;
  atomicAdd(&cnt[r * N_NODES + ei[E_EDGES + e]], 1);
}

__global__ __launch_bounds__(256)
void scan_kernel(const int* __restrict__ cnt, int* __restrict__ rp, int* __restrict__ cur) {
  const int r = blockIdx.x;
  const int* c = cnt + r * N_NODES;
  int* rpp = rp + r * (N_NODES + 1);
  int* u = cur + r * N_NODES;
  __shared__ int part[256];
  const int tid = threadIdx.x;
  const int base = tid * 64;
  int s = 0;
  for (int i = 0; i < 64; i++) s += c[base + i];
  part[tid] = s;
  __syncthreads();
  for (int off = 1; off < 256; off <<= 1) {
    int v = (tid >= off) ? part[tid - off] : 0;
    __syncthreads();
    part[tid] += v;
    __syncthreads();
  }
  int run = (tid == 0) ? 0 : part[tid - 1];
  for (int i = 0; i < 64; i++) {
    int idx = base + i;
    rpp[idx] = run;
    u[idx] = run;
    run += c[idx];
  }
  if (tid == 255) rpp[N_NODES] = run;
}

__global__ __launch_bounds__(256)
void fill_kernel(const int* __restrict__ e0, const int* __restrict__ e1,
                 const int* __restrict__ e2, const int* __restrict__ e3,
                 int* __restrict__ cur, int* __restrict__ srcl) {
  int g = blockIdx.x * 256 + threadIdx.x;
  int r = g >> 16, e = g & 0xFFFF;
  const int* ei = (r == 0) ? e0 : (r == 1) ? e1 : (r == 2) ? e2 : e3;
  int pos = atomicAdd(&cur[r * N_NODES + ei[E_EDGES + e]], 1);
  srcl[r * E_EDGES + pos] = ei[e];   // store src directly
}

// ================= per-relation attention pass (online softmax, persistent state) =========
// one wave per dst node; lane l: head h=l>>3, 4 dims at l*4
template<bool FIRST, bool FINAL>
__global__ __launch_bounds__(256)
void attn_rel(const float* __restrict__ q, const float* __restrict__ kr,
              const float* __restrict__ mr, const float* __restrict__ prel,
              const int* __restrict__ rp, const int* __restrict__ srcl,
              float* __restrict__ mbuf, float* __restrict__ dbuf,
              float* __restrict__ acc) {
  const int n = (blockIdx.x * 256 + threadIdx.x) >> 6;
  const int lane = threadIdx.x & 63;
  const int h = lane >> 3;
  const float p = prel[h] * 0.17677669529663687f;   // * 1/sqrt(32)
  float4 qv = *(const float4*)(q + (size_t)n * HIDC + lane * 4);
  float m, den;
  float4 a;
  if (FIRST) {
    m = -INFINITY; den = 0.0f; a = make_float4(0.f, 0.f, 0.f, 0.f);
  } else {
    m = mbuf[n * 8 + h];
    den = dbuf[n * 8 + h];
    a = *(const float4*)(acc + (size_t)n * HIDC + lane * 4);
  }
  const int beg = rp[n], end = rp[n + 1];
  for (int i = beg; i < end; i++) {
    int src = srcl[i];
    size_t off = (size_t)src * HIDC + lane * 4;
    float4 kv = *(const float4*)(kr + off);
    float dot = qv.x * kv.x + qv.y * kv.y + qv.z * kv.z + qv.w * kv.w;
    dot += __shfl_xor(dot, 1);
    dot += __shfl_xor(dot, 2);
    dot += __shfl_xor(dot, 4);
    float s = dot * p;
    float mn = fmaxf(m, s);
    float c = expf(m - mn);
    float w = expf(s - mn);
    den = den * c + w;
    float4 mv = *(const float4*)(mr + off);
    a.x = a.x * c + w * mv.x;
    a.y = a.y * c + w * mv.y;
    a.z = a.z * c + w * mv.z;
    a.w = a.w * c + w * mv.w;
    m = mn;
  }
  if (FINAL) {
    float inv = 1.0f / fmaxf(den, 1e-16f);
    float4 o = make_float4(a.x * inv, a.y * inv, a.z * inv, a.w * inv);
    *(float4*)(acc + (size_t)n * HIDC + lane * 4) = o;
  } else {
    *(float4*)(acc + (size_t)n * HIDC + lane * 4) = a;
    if ((lane & 7) == 0) { mbuf[n * 8 + h] = m; dbuf[n * 8 + h] = den; }
  }
}

// ================= skip-gate + residual + LayerNorm (in-place on h) =================
__global__ __launch_bounds__(256)
void ln_kernel(const float* __restrict__ ob, float* __restrict__ h,
               const float* __restrict__ skipv, const float* __restrict__ g,
               const float* __restrict__ b) {
  const int row = blockIdx.x, tid = threadIdx.x;
  float a = 1.0f / (1.0f + expf(-skipv[0]));
  size_t off = (size_t)row * HIDC + tid;
  float hv = h[off], ov = ob[off];
  float y = a * ov + (1.0f - a) * hv + hv;   // conv + residual
  __shared__ float red[256];
  red[tid] = y;
  __syncthreads();
  #pragma unroll
  for (int o = 128; o > 0; o >>= 1) {
    if (tid < o) red[tid] += red[tid + o];
    __syncthreads();
  }
  float mu = red[0] * (1.0f / 256.0f);
  __syncthreads();
  float dv = y - mu;
  red[tid] = dv * dv;
  __syncthreads();
  #pragma unroll
  for (int o = 128; o > 0; o >>= 1) {
    if (tid < o) red[tid] += red[tid + o];
    __syncthreads();
  }
  float var = red[0] * (1.0f / 256.0f);
  float rs = 1.0f / sqrtf(var + 1e-5f);
  h[off] = dv * rs * g[tid] + b[tid];
}

extern "C" void kernel_launch(void* const* d_in, const int* in_sizes, int n_in,
                              void* d_out, int out_size, void* d_ws, size_t ws_size,
                              hipStream_t stream) {
  const float* x[3] = {(const float*)d_in[0], (const float*)d_in[1], (const float*)d_in[2]};
  const int* ei[4] = {(const int*)d_in[3], (const int*)d_in[4], (const int*)d_in[5], (const int*)d_in[6]};
  const float* Win  = (const float*)d_in[7];
  const float* b_in = (const float*)d_in[8];
  const float* Kw   = (const float*)d_in[9];
  const float* Kb   = (const float*)d_in[10];
  const float* Qw   = (const float*)d_in[11];
  const float* Qb   = (const float*)d_in[12];
  const float* Vw   = (const float*)d_in[13];
  const float* Vb   = (const float*)d_in[14];
  const float* Arel = (const float*)d_in[15];
  const float* Mrel = (const float*)d_in[16];
  const float* Prel = (const float*)d_in[17];
  const float* Aw   = (const float*)d_in[18];
  const float* Ab   = (const float*)d_in[19];
  const float* skip = (const float*)d_in[20];
  const float* ln_g = (const float*)d_in[21];
  const float* ln_b = (const float*)d_in[22];
  const float* Wout = (const float*)d_in[23];
  const float* b_out= (const float*)d_in[24];

  // ---- lean workspace layout: ~112 MB total ----
  float* f    = (float*)d_ws;
  float* hs   = f;                 // 3 NM
  float* qb   = f + 3 * NM;        // 1 NM  (q buffer, reused as gelu-GEMM tmp)
  float* kr   = f + 4 * NM;        // 1 NM
  float* mr   = f + 5 * NM;        // 1 NM
  float* fw   = f + 6 * NM;        // 32 * 65536 = 2097152
  float* fb   = fw + 2097152;      // 32 * 256   = 8192
  float* mbuf = fb + 8192;         // N*8 = 131072
  float* dbuf = mbuf + 131072;     // 131072
  int*   ib   = (int*)(dbuf + 131072);
  int*   cnt  = ib;                        // 4*N
  int*   rp   = ib + 4 * N_NODES;          // 4*(N+1)
  int*   cur  = rp + 4 * (N_NODES + 1);    // 4*N
  int*   srcl = cur + 4 * N_NODES;         // 4*E
  float* acc  = (float*)d_out;     // 3 NM scratch, fully overwritten by out-proj at end

  const dim3 gG(2, 128);           // GEMM grid: 256 blocks (1/CU)
  const int SRC[4] = {1, 0, 2, 0};

  // fused weights for all layers/relations (K and V folded with Arel/Mrel)
  fuse_kernel<<<dim3(8, 16, 2), 256, 0, stream>>>(Kw, Kb, Vw, Vb, Arel, Mrel, fw, fb);

  // per-relation CSR (indices launch-invariant, but ws is re-poisoned each call)
  zero_cnt_kernel<<<4 * N_NODES / 256, 256, 0, stream>>>(cnt);
  count_kernel<<<4 * E_EDGES / 256, 256, 0, stream>>>(ei[0], ei[1], ei[2], ei[3], cnt);
  scan_kernel<<<4, 256, 0, stream>>>(cnt, rp, cur);
  fill_kernel<<<4 * E_EDGES / 256, 256, 0, stream>>>(ei[0], ei[1], ei[2], ei[3], cur, srcl);

  // input projections
  for (int t = 0; t < 3; t++)
    gemm128<false><<<gG, 256, 0, stream>>>(x[t], Win + (size_t)t * 65536, b_in + t * 256, hs + t * NM);

  // relation processing order per layer: r0(dst0), r3(dst0), r2(dst1), r1(dst2)
  const int RORD[4]   = {0, 3, 2, 1};
  const int RDST[4]   = {0, 0, 1, 2};
  const bool RFIRST[4] = {true, false, true, true};
  const bool RFINAL[4] = {false, true, true, true};

  for (int l = 0; l < 4; l++) {
    int qdone = -1;
    for (int k = 0; k < 4; k++) {
      int r = RORD[k], dt = RDST[k], s = SRC[r];
      int lr = l * 4 + r;
      if (dt != qdone) {   // q projection for this dst type
        size_t wo = (size_t)(l * 3 + dt) * 65536, bo = (size_t)(l * 3 + dt) * 256;
        gemm128<false><<<gG, 256, 0, stream>>>(hs + dt * NM, Qw + wo, Qb + bo, qb);
        qdone = dt;
      }
      // relation-fused K and V projections of the src type
      gemm128<false><<<gG, 256, 0, stream>>>(hs + s * NM, fw + (size_t)(lr * 2 + 0) * 65536,
                                             fb + (lr * 2 + 0) * 256, kr);
      gemm128<false><<<gG, 256, 0, stream>>>(hs + s * NM, fw + (size_t)(lr * 2 + 1) * 65536,
                                             fb + (lr * 2 + 1) * 256, mr);
      const float* pr = Prel + lr * 8;
      const int* rpp = rp + r * (N_NODES + 1);
      const int* sl  = srcl + r * E_EDGES;
      float* at = acc + (size_t)dt * NM;
      if (RFIRST[k] && RFINAL[k])
        attn_rel<true, true><<<N_NODES / 4, 256, 0, stream>>>(qb, kr, mr, pr, rpp, sl, mbuf, dbuf, at);
      else if (RFIRST[k])
        attn_rel<true, false><<<N_NODES / 4, 256, 0, stream>>>(qb, kr, mr, pr, rpp, sl, mbuf, dbuf, at);
      else
        attn_rel<false, true><<<N_NODES / 4, 256, 0, stream>>>(qb, kr, mr, pr, rpp, sl, mbuf, dbuf, at);
    }
    // epilogue per type: gelu(agg) @ Aw + Ab, skip-gate, residual, LN
    for (int t = 0; t < 3; t++) {
      size_t wo = (size_t)(l * 3 + t) * 65536, bo = (size_t)(l * 3 + t) * 256;
      gemm128<true><<<gG, 256, 0, stream>>>(acc + (size_t)t * NM, Aw + wo, Ab + bo, qb);
      ln_kernel<<<N_NODES, 256, 0, stream>>>(qb, hs + t * NM, skip + l * 3 + t, ln_g + bo, ln_b + bo);
    }
  }

  // output projections straight into d_out
  for (int t = 0; t < 3; t++)
    gemm128<false><<<gG, 256, 0, stream>>>(hs + t * NM, Wout + (size_t)t * 65536,
                                           b_out + t * 256, (float*)d_out + t * NM);
}

// Round 4
// 1947.463 us; speedup vs baseline: 1.9217x; 1.9217x over previous
//
#include <hip/hip_runtime.h>

#define N_NODES 16384
#define E_EDGES 65536
#define HIDC 256
#define NM ((size_t)N_NODES * HIDC)   // 4194304 floats
#define NSLOT 62
#define PLANE ((size_t)NSLOT * 65536)  // elements per bf16 plane

typedef __attribute__((ext_vector_type(8))) short short8;
typedef __attribute__((ext_vector_type(4))) float f32x4;

__device__ __forceinline__ float gelu_f(float x) {
  // jax.nn.gelu (approximate=True)
  return 0.5f * x * (1.0f + tanhf(0.7978845608028654f * (x + 0.044715f * x * x * x)));
}

// split fp32 -> bf16 hi + bf16 lo (RNE both); x ~= hi + lo with ~2^-17 rel error
__device__ __forceinline__ void split2(float x, unsigned short& h, unsigned short& l) {
  unsigned u = __float_as_uint(x);
  unsigned hr = (u + 0x7FFFu + ((u >> 16) & 1u)) >> 16;
  h = (unsigned short)hr;
  float rem = x - __uint_as_float(hr << 16);
  unsigned v = __float_as_uint(rem);
  l = (unsigned short)((v + 0x7FFFu + ((v >> 16) & 1u)) >> 16);
}

// wprep element offset within a matrix slot: layout [nt(4)][ks(8)][kq(4)][n(64)][i(8)]
__device__ __forceinline__ size_t woff(int k, int n) {
  return (size_t)((n >> 6) * 16384 + (k >> 5) * 2048 + (((k >> 3) & 3) * 512) + ((n & 63) * 8) + (k & 7));
}

// ================= split-bf16 MFMA GEMM: C[16384x256] = act(A) @ W + bias =================
// block 64x64, 256 thr = 4 waves (2x2), wave 32x32 = 2x2 frags of 16x16x32.
template<bool GELU_IN>
__global__ __launch_bounds__(256)
void gemm_mfma(const float* __restrict__ A, const unsigned short* __restrict__ Whi,
               const unsigned short* __restrict__ Wlo, const float* __restrict__ bias,
               float* __restrict__ C) {
  __shared__ short Ah[2048], Al[2048];   // [kq(4)][m(64)][i(8)]
  __shared__ short Bh[2048], Bl[2048];   // [kq(4)][n(64)][i(8)]
  const int tid = threadIdx.x;
  const int nt = blockIdx.x;
  const int bn = nt * 64;
  const int bm = blockIdx.y * 64;
  const int w = tid >> 6, l = tid & 63;
  const int mw = (w >> 1) * 32, nw = (w & 1) * 32;
  const int lk = l >> 4, ln = l & 15;
  const int sm = tid & 63;     // staging: m row
  const int skq = tid >> 6;    // staging: kq group

  f32x4 acc[2][2];
  #pragma unroll
  for (int a = 0; a < 2; a++)
    #pragma unroll
    for (int b = 0; b < 2; b++) acc[a][b] = f32x4{0.f, 0.f, 0.f, 0.f};

  for (int ks = 0; ks < 8; ks++) {
    const int k0 = ks * 32;
    // global loads first (no LDS dependence)
    const float* ap = A + (size_t)(bm + sm) * HIDC + k0 + skq * 8;
    float4 v0 = *(const float4*)ap;
    float4 v1 = *(const float4*)(ap + 4);
    const size_t wchunk = (size_t)nt * 16384 + ks * 2048 + tid * 8;
    short8 wh = *(const short8*)(Whi + wchunk);
    short8 wl = *(const short8*)(Wlo + wchunk);
    if (ks) __syncthreads();   // previous iteration's frag reads done
    float xs[8] = {v0.x, v0.y, v0.z, v0.w, v1.x, v1.y, v1.z, v1.w};
    short8 ah, al8;
    #pragma unroll
    for (int i = 0; i < 8; i++) {
      float x = xs[i];
      if (GELU_IN) x = gelu_f(x);
      unsigned short h16, l16;
      split2(x, h16, l16);
      ah[i] = (short)h16; al8[i] = (short)l16;
    }
    *(short8*)&Ah[(skq * 64 + sm) * 8] = ah;
    *(short8*)&Al[(skq * 64 + sm) * 8] = al8;
    *(short8*)&Bh[tid * 8] = wh;
    *(short8*)&Bl[tid * 8] = wl;
    __syncthreads();
    short8 a_h[2], a_l[2], b_h[2], b_l[2];
    #pragma unroll
    for (int mf = 0; mf < 2; mf++) {
      int idx = (lk * 64 + mw + mf * 16 + ln) * 8;
      a_h[mf] = *(const short8*)&Ah[idx];
      a_l[mf] = *(const short8*)&Al[idx];
    }
    #pragma unroll
    for (int nf = 0; nf < 2; nf++) {
      int idx = (lk * 64 + nw + nf * 16 + ln) * 8;
      b_h[nf] = *(const short8*)&Bh[idx];
      b_l[nf] = *(const short8*)&Bl[idx];
    }
    #pragma unroll
    for (int mf = 0; mf < 2; mf++)
      #pragma unroll
      for (int nf = 0; nf < 2; nf++) {
        acc[mf][nf] = __builtin_amdgcn_mfma_f32_16x16x32_bf16(a_l[mf], b_h[nf], acc[mf][nf], 0, 0, 0);
        acc[mf][nf] = __builtin_amdgcn_mfma_f32_16x16x32_bf16(a_h[mf], b_l[nf], acc[mf][nf], 0, 0, 0);
        acc[mf][nf] = __builtin_amdgcn_mfma_f32_16x16x32_bf16(a_h[mf], b_h[nf], acc[mf][nf], 0, 0, 0);
      }
  }
  #pragma unroll
  for (int nf = 0; nf < 2; nf++) {
    const int col = bn + nw + nf * 16 + ln;
    const float bv = bias[col];
    #pragma unroll
    for (int mf = 0; mf < 2; mf++) {
      const int row = bm + mw + mf * 16 + lk * 4;
      #pragma unroll
      for (int r = 0; r < 4; r++)
        C[(size_t)(row + r) * HIDC + col] = acc[mf][nf][r] + bv;
    }
  }
}

// ================= plain-weight prep: split 30 matrices into MFMA-native layout ==========
// slots: 0..2 Win, 3..14 Qw, 15..26 Aw, 27..29 Wout. grid (32 chunks, 30), block 256.
__global__ __launch_bounds__(256)
void prep_plain(const float* __restrict__ Win, const float* __restrict__ Qw,
                const float* __restrict__ Aw, const float* __restrict__ Wout,
                unsigned short* __restrict__ wh, unsigned short* __restrict__ wlo) {
  const int j = blockIdx.y;
  const float* src = j < 3  ? Win  + (size_t)j * 65536 :
                     j < 15 ? Qw   + (size_t)(j - 3) * 65536 :
                     j < 27 ? Aw   + (size_t)(j - 15) * 65536 :
                              Wout + (size_t)(j - 27) * 65536;
  const int c = blockIdx.x;          // nt = c>>3, ks = c&7
  const int nt = c >> 3, ks = c & 7;
  const int t = threadIdx.x;
  const int n = nt * 64 + (t & 63);
  const int kq = t >> 6;
  const int k = ks * 32 + kq * 8;
  short8 h8, l8;
  #pragma unroll
  for (int i = 0; i < 8; i++) {
    unsigned short h, lo;
    split2(src[(size_t)(k + i) * HIDC + n], h, lo);
    h8[i] = (short)h; l8[i] = (short)lo;
  }
  size_t off = (size_t)j * 65536 + nt * 16384 + ks * 2048 + kq * 512 + (size_t)(t & 63) * 8;
  *(short8*)&wh[off] = h8;
  *(short8*)&wlo[off] = l8;
}

// ================= fused K/V weight build: W' = Wsrc . blockdiag(A), split output ==========
// grid (8 heads, 16 l*4+r, 2 K/V), block 256. slots: K -> 30+lr, V -> 46+lr.
__global__ __launch_bounds__(256)
void fuse_kernel(const float* __restrict__ Kw, const float* __restrict__ Kb,
                 const float* __restrict__ Vw, const float* __restrict__ Vb,
                 const float* __restrict__ Arel, const float* __restrict__ Mrel,
                 unsigned short* __restrict__ wh, unsigned short* __restrict__ wlo,
                 float* __restrict__ fb) {
  const int h = blockIdx.x;
  const int lr = blockIdx.y;            // l*4 + r
  const int kv = blockIdx.z;
  const int l = lr >> 2, r = lr & 3;
  const int s = (r == 0) ? 1 : (r == 2) ? 2 : 0;   // REL src types {1,0,2,0}
  const float* Wsrc = (kv ? Vw : Kw) + (size_t)(l * 3 + s) * 65536;
  const float* bsrc = (kv ? Vb : Kb) + (size_t)(l * 3 + s) * 256;
  const float* A    = (kv ? Mrel : Arel) + (size_t)lr * 8192 + h * 1024;
  const int slot = (kv ? 46 : 30) + lr;
  float* fbp = fb + (size_t)(lr * 2 + kv) * 256;
  __shared__ float Am[32][32];
  const int tid = threadIdx.x;
  #pragma unroll
  for (int i = 0; i < 4; i++) { int p = tid + i * 256; Am[p >> 5][p & 31] = A[p]; }
  __syncthreads();
  float w[32];
  #pragma unroll
  for (int d = 0; d < 32; d++) w[d] = Wsrc[(size_t)tid * HIDC + h * 32 + d];
  const size_t sbase = (size_t)slot * 65536;
  #pragma unroll
  for (int e = 0; e < 32; e++) {
    float sacc = 0.0f;
    #pragma unroll
    for (int d = 0; d < 32; d++) sacc += w[d] * Am[d][e];
    unsigned short hi, lo;
    split2(sacc, hi, lo);
    size_t o = sbase + woff(tid, h * 32 + e);
    wh[o] = hi; wlo[o] = lo;
  }
  if (tid < 32) {
    float sacc = 0.0f;
    #pragma unroll
    for (int d = 0; d < 32; d++) sacc += bsrc[h * 32 + d] * Am[d][tid];
    fbp[h * 32 + tid] = sacc;
  }
}

// ================= per-relation CSR build =================
__global__ __launch_bounds__(256)
void zero_cnt_kernel(int* __restrict__ cnt) {
  cnt[blockIdx.x * 256 + threadIdx.x] = 0;
}

__global__ __launch_bounds__(256)
void count_kernel(const int* __restrict__ e0, const int* __restrict__ e1,
                  const int* __restrict__ e2, const int* __restrict__ e3,
                  int* __restrict__ cnt) {
  int g = blockIdx.x * 256 + threadIdx.x;
  int r = g >> 16, e = g & 0xFFFF;
  const int* ei = (r == 0) ? e0 : (r == 1) ? e1 : (r == 2) ? e2 : e3;
  atomicAdd(&cnt[r * N_NODES + ei[E_EDGES + e]], 1);
}

__global__ __launch_bounds__(256)
void scan_kernel(const int* __restrict__ cnt, int* __restrict__ rp, int* __restrict__ cur) {
  const int r = blockIdx.x;
  const int* c = cnt + r * N_NODES;
  int* rpp = rp + r * (N_NODES + 1);
  int* u = cur + r * N_NODES;
  __shared__ int part[256];
  const int tid = threadIdx.x;
  const int base = tid * 64;
  int s = 0;
  for (int i = 0; i < 64; i++) s += c[base + i];
  part[tid] = s;
  __syncthreads();
  for (int off = 1; off < 256; off <<= 1) {
    int v = (tid >= off) ? part[tid - off] : 0;
    __syncthreads();
    part[tid] += v;
    __syncthreads();
  }
  int run = (tid == 0) ? 0 : part[tid - 1];
  for (int i = 0; i < 64; i++) {
    int idx = base + i;
    rpp[idx] = run;
    u[idx] = run;
    run += c[idx];
  }
  if (tid == 255) rpp[N_NODES] = run;
}

__global__ __launch_bounds__(256)
void fill_kernel(const int* __restrict__ e0, const int* __restrict__ e1,
                 const int* __restrict__ e2, const int* __restrict__ e3,
                 int* __restrict__ cur, int* __restrict__ srcl) {
  int g = blockIdx.x * 256 + threadIdx.x;
  int r = g >> 16, e = g & 0xFFFF;
  const int* ei = (r == 0) ? e0 : (r == 1) ? e1 : (r == 2) ? e2 : e3;
  int pos = atomicAdd(&cur[r * N_NODES + ei[E_EDGES + e]], 1);
  srcl[r * E_EDGES + pos] = ei[e];
}

// ================= per-relation attention pass (online softmax, persistent state) =========
template<bool FIRST, bool FINAL>
__global__ __launch_bounds__(256)
void attn_rel(const float* __restrict__ q, const float* __restrict__ kr,
              const float* __restrict__ mr, const float* __restrict__ prel,
              const int* __restrict__ rp, const int* __restrict__ srcl,
              float* __restrict__ mbuf, float* __restrict__ dbuf,
              float* __restrict__ acc) {
  const int n = (blockIdx.x * 256 + threadIdx.x) >> 6;
  const int lane = threadIdx.x & 63;
  const int h = lane >> 3;
  const float p = prel[h] * 0.17677669529663687f;   // * 1/sqrt(32)
  float4 qv = *(const float4*)(q + (size_t)n * HIDC + lane * 4);
  float m, den;
  float4 a;
  if (FIRST) {
    m = -INFINITY; den = 0.0f; a = make_float4(0.f, 0.f, 0.f, 0.f);
  } else {
    m = mbuf[n * 8 + h];
    den = dbuf[n * 8 + h];
    a = *(const float4*)(acc + (size_t)n * HIDC + lane * 4);
  }
  const int beg = rp[n], end = rp[n + 1];
  for (int i = beg; i < end; i++) {
    int src = srcl[i];
    size_t off = (size_t)src * HIDC + lane * 4;
    float4 kv = *(const float4*)(kr + off);
    float dot = qv.x * kv.x + qv.y * kv.y + qv.z * kv.z + qv.w * kv.w;
    dot += __shfl_xor(dot, 1);
    dot += __shfl_xor(dot, 2);
    dot += __shfl_xor(dot, 4);
    float s = dot * p;
    float mn = fmaxf(m, s);
    float c = expf(m - mn);
    float wgt = expf(s - mn);
    den = den * c + wgt;
    float4 mv = *(const float4*)(mr + off);
    a.x = a.x * c + wgt * mv.x;
    a.y = a.y * c + wgt * mv.y;
    a.z = a.z * c + wgt * mv.z;
    a.w = a.w * c + wgt * mv.w;
    m = mn;
  }
  if (FINAL) {
    float inv = 1.0f / fmaxf(den, 1e-16f);
    float4 o = make_float4(a.x * inv, a.y * inv, a.z * inv, a.w * inv);
    *(float4*)(acc + (size_t)n * HIDC + lane * 4) = o;
  } else {
    *(float4*)(acc + (size_t)n * HIDC + lane * 4) = a;
    if ((lane & 7) == 0) { mbuf[n * 8 + h] = m; dbuf[n * 8 + h] = den; }
  }
}

// ================= skip-gate + residual + LayerNorm (in-place on h) =================
__global__ __launch_bounds__(256)
void ln_kernel(const float* __restrict__ ob, float* __restrict__ h,
               const float* __restrict__ skipv, const float* __restrict__ g,
               const float* __restrict__ b) {
  const int row = blockIdx.x, tid = threadIdx.x;
  float a = 1.0f / (1.0f + expf(-skipv[0]));
  size_t off = (size_t)row * HIDC + tid;
  float hv = h[off], ov = ob[off];
  float y = a * ov + (1.0f - a) * hv + hv;   // conv + residual
  __shared__ float red[256];
  red[tid] = y;
  __syncthreads();
  #pragma unroll
  for (int o = 128; o > 0; o >>= 1) {
    if (tid < o) red[tid] += red[tid + o];
    __syncthreads();
  }
  float mu = red[0] * (1.0f / 256.0f);
  __syncthreads();
  float dv = y - mu;
  red[tid] = dv * dv;
  __syncthreads();
  #pragma unroll
  for (int o = 128; o > 0; o >>= 1) {
    if (tid < o) red[tid] += red[tid + o];
    __syncthreads();
  }
  float var = red[0] * (1.0f / 256.0f);
  float rs = 1.0f / sqrtf(var + 1e-5f);
  h[off] = dv * rs * g[tid] + b[tid];
}

extern "C" void kernel_launch(void* const* d_in, const int* in_sizes, int n_in,
                              void* d_out, int out_size, void* d_ws, size_t ws_size,
                              hipStream_t stream) {
  const float* x[3] = {(const float*)d_in[0], (const float*)d_in[1], (const float*)d_in[2]};
  const int* ei[4] = {(const int*)d_in[3], (const int*)d_in[4], (const int*)d_in[5], (const int*)d_in[6]};
  const float* Win  = (const float*)d_in[7];
  const float* b_in = (const float*)d_in[8];
  const float* Kw   = (const float*)d_in[9];
  const float* Kb   = (const float*)d_in[10];
  const float* Qw   = (const float*)d_in[11];
  const float* Qb   = (const float*)d_in[12];
  const float* Vw   = (const float*)d_in[13];
  const float* Vb   = (const float*)d_in[14];
  const float* Arel = (const float*)d_in[15];
  const float* Mrel = (const float*)d_in[16];
  const float* Prel = (const float*)d_in[17];
  const float* Aw   = (const float*)d_in[18];
  const float* Ab   = (const float*)d_in[19];
  const float* skip = (const float*)d_in[20];
  const float* ln_g = (const float*)d_in[21];
  const float* ln_b = (const float*)d_in[22];
  const float* Wout = (const float*)d_in[23];
  const float* b_out= (const float*)d_in[24];

  // ---- workspace layout: ~115 MB ----
  float* f    = (float*)d_ws;
  float* hs   = f;                 // 3 NM
  float* qb   = f + 3 * NM;        // 1 NM (q; reused as gelu-GEMM tmp)
  float* kr   = f + 4 * NM;        // 1 NM
  float* mr   = f + 5 * NM;        // 1 NM
  unsigned short* wprep = (unsigned short*)(f + 6 * NM);   // 2 planes * 62 * 65536 shorts
  float* fb   = (float*)(wprep + 2 * PLANE);   // 32*256
  float* mbuf = fb + 8192;         // N*8
  float* dbuf = mbuf + 131072;     // N*8
  int*   ib   = (int*)(dbuf + 131072);
  int*   cnt  = ib;                        // 4*N
  int*   rp   = ib + 4 * N_NODES;          // 4*(N+1)
  int*   cur  = rp + 4 * (N_NODES + 1);    // 4*N
  int*   srcl = cur + 4 * N_NODES;         // 4*E
  float* acc  = (float*)d_out;     // 3 NM scratch; fully overwritten by out-proj

  const dim3 gG(4, 256);           // GEMM grid: 1024 blocks (4/CU)
  const int SRC[4] = {1, 0, 2, 0};

  auto G = [&](const float* Ap, int slot, const float* bp, float* Cp, bool gelu) {
    const unsigned short* wh = wprep + (size_t)slot * 65536;
    const unsigned short* wl = wprep + PLANE + (size_t)slot * 65536;
    if (gelu) gemm_mfma<true><<<gG, 256, 0, stream>>>(Ap, wh, wl, bp, Cp);
    else      gemm_mfma<false><<<gG, 256, 0, stream>>>(Ap, wh, wl, bp, Cp);
  };

  // weight prep (every call; ws is re-poisoned)
  prep_plain<<<dim3(32, 30), 256, 0, stream>>>(Win, Qw, Aw, Wout, wprep, wprep + PLANE);
  fuse_kernel<<<dim3(8, 16, 2), 256, 0, stream>>>(Kw, Kb, Vw, Vb, Arel, Mrel,
                                                  wprep, wprep + PLANE, fb);

  // per-relation CSR
  zero_cnt_kernel<<<4 * N_NODES / 256, 256, 0, stream>>>(cnt);
  count_kernel<<<4 * E_EDGES / 256, 256, 0, stream>>>(ei[0], ei[1], ei[2], ei[3], cnt);
  scan_kernel<<<4, 256, 0, stream>>>(cnt, rp, cur);
  fill_kernel<<<4 * E_EDGES / 256, 256, 0, stream>>>(ei[0], ei[1], ei[2], ei[3], cur, srcl);

  // input projections
  for (int t = 0; t < 3; t++)
    G(x[t], t, b_in + t * 256, hs + t * NM, false);

  // relation order per layer: r0(dst0), r3(dst0), r2(dst1), r1(dst2)
  const int RORD[4]    = {0, 3, 2, 1};
  const int RDST[4]    = {0, 0, 1, 2};
  const bool RFIRST[4] = {true, false, true, true};
  const bool RFINAL[4] = {false, true, true, true};

  for (int l = 0; l < 4; l++) {
    int qdone = -1;
    for (int k = 0; k < 4; k++) {
      int r = RORD[k], dt = RDST[k], s = SRC[r];
      int lr = l * 4 + r;
      if (dt != qdone) {
        G(hs + dt * NM, 3 + l * 3 + dt, Qb + (l * 3 + dt) * 256, qb, false);
        qdone = dt;
      }
      G(hs + s * NM, 30 + lr, fb + (lr * 2 + 0) * 256, kr, false);
      G(hs + s * NM, 46 + lr, fb + (lr * 2 + 1) * 256, mr, false);
      const float* pr = Prel + lr * 8;
      const int* rpp = rp + r * (N_NODES + 1);
      const int* sl  = srcl + r * E_EDGES;
      float* at = acc + (size_t)dt * NM;
      if (RFIRST[k] && RFINAL[k])
        attn_rel<true, true><<<N_NODES / 4, 256, 0, stream>>>(qb, kr, mr, pr, rpp, sl, mbuf, dbuf, at);
      else if (RFIRST[k])
        attn_rel<true, false><<<N_NODES / 4, 256, 0, stream>>>(qb, kr, mr, pr, rpp, sl, mbuf, dbuf, at);
      else
        attn_rel<false, true><<<N_NODES / 4, 256, 0, stream>>>(qb, kr, mr, pr, rpp, sl, mbuf, dbuf, at);
    }
    for (int t = 0; t < 3; t++) {
      size_t bo = (size_t)(l * 3 + t) * 256;
      G(acc + (size_t)t * NM, 15 + l * 3 + t, Ab + bo, qb, true);
      ln_kernel<<<N_NODES, 256, 0, stream>>>(qb, hs + t * NM, skip + l * 3 + t, ln_g + bo, ln_b + bo);
    }
  }

  for (int t = 0; t < 3; t++)
    G(hs + t * NM, 27 + t, b_out + t * 256, (float*)d_out + t * NM, false);
}

// Round 5
// 1835.322 us; speedup vs baseline: 2.0391x; 1.0611x over previous
//
#include <hip/hip_runtime.h>

#define N_NODES 16384
#define E_EDGES 65536
#define HIDC 256
#define NM ((size_t)N_NODES * HIDC)       // 4194304 floats
#define NSLOT 62
#define PLANEU ((size_t)NSLOT * 65536)    // ushorts per wprep plane

typedef __attribute__((ext_vector_type(8))) short short8;
typedef __attribute__((ext_vector_type(4))) float f32x4;

__device__ __forceinline__ float gelu_f(float x) {
  return 0.5f * x * (1.0f + tanhf(0.7978845608028654f * (x + 0.044715f * x * x * x)));
}

// fp32 -> bf16 RNE
__device__ __forceinline__ unsigned short bf16rne(float x) {
  unsigned u = __float_as_uint(x);
  return (unsigned short)((u + 0x7FFFu + ((u >> 16) & 1u)) >> 16);
}
// split fp32 -> bf16 hi + bf16 lo; x ~= hi + lo (~2^-17 rel err)
__device__ __forceinline__ void split2(float x, unsigned short& h, unsigned short& l) {
  h = bf16rne(x);
  float rem = x - __uint_as_float(((unsigned)h) << 16);
  l = bf16rne(rem);
}
__device__ __forceinline__ float bf2f(unsigned short v) {
  return __uint_as_float(((unsigned)v) << 16);
}

// wprep element offset within a slot: [nt(4)][ks(8)][kq(4)][n(64)][i(8)]
__device__ __forceinline__ size_t woff(int k, int n) {
  return (size_t)((n >> 6) * 16384 + (k >> 5) * 2048 + (((k >> 3) & 3) * 512) + ((n & 63) * 8) + (k & 7));
}

// ================= split-bf16 MFMA GEMM, pre-split A planes =================
// block 64x64(xN-tiles), 256 thr = 4 waves, wave 32x32 = 2x2 frags of 16x16x32.
// OUTM: 0 = fp32 (gN=256), 1 = hi/lo planes (gN=256), 2 = bf16 k/m buffer (gN=512)
template<int OUTM>
__global__ __launch_bounds__(256)
void gemm_ps(const unsigned short* __restrict__ Ahi, const unsigned short* __restrict__ Alo,
             const unsigned short* __restrict__ Whi, const unsigned short* __restrict__ Wlo,
             const float* __restrict__ bias, float* __restrict__ Cf,
             unsigned short* __restrict__ Chi, unsigned short* __restrict__ Clo,
             unsigned short* __restrict__ Ckm) {
  __shared__ short Ah[2048], Al[2048];   // [kq(4)][m(64)][i(8)]
  __shared__ short Bh[2048], Bl[2048];   // [kq(4)][n(64)][i(8)]
  const int tid = threadIdx.x;
  const int nt = blockIdx.x;
  const int bm = blockIdx.y * 64;
  const int w = tid >> 6, l = tid & 63;
  const int mw = (w >> 1) * 32, nw = (w & 1) * 32;
  const int lk = l >> 4, ln = l & 15;
  const int sm = tid & 63, skq = tid >> 6;

  f32x4 acc[2][2];
  #pragma unroll
  for (int a = 0; a < 2; a++)
    #pragma unroll
    for (int b = 0; b < 2; b++) acc[a][b] = f32x4{0.f, 0.f, 0.f, 0.f};

  for (int ks = 0; ks < 8; ks++) {
    const size_t aoff = (size_t)(bm + sm) * HIDC + ks * 32 + skq * 8;
    short8 ah = *(const short8*)(Ahi + aoff);
    short8 al = *(const short8*)(Alo + aoff);
    const size_t wo = (size_t)(nt >> 2) * 65536 + (nt & 3) * 16384 + ks * 2048 + tid * 8;
    short8 wh = *(const short8*)(Whi + wo);
    short8 wl = *(const short8*)(Wlo + wo);
    if (ks) __syncthreads();
    *(short8*)&Ah[tid * 8] = ah;
    *(short8*)&Al[tid * 8] = al;
    *(short8*)&Bh[tid * 8] = wh;
    *(short8*)&Bl[tid * 8] = wl;
    __syncthreads();
    short8 a_h[2], a_l[2], b_h[2], b_l[2];
    #pragma unroll
    for (int mf = 0; mf < 2; mf++) {
      int idx = (lk * 64 + mw + mf * 16 + ln) * 8;
      a_h[mf] = *(const short8*)&Ah[idx];
      a_l[mf] = *(const short8*)&Al[idx];
    }
    #pragma unroll
    for (int nf = 0; nf < 2; nf++) {
      int idx = (lk * 64 + nw + nf * 16 + ln) * 8;
      b_h[nf] = *(const short8*)&Bh[idx];
      b_l[nf] = *(const short8*)&Bl[idx];
    }
    #pragma unroll
    for (int mf = 0; mf < 2; mf++)
      #pragma unroll
      for (int nf = 0; nf < 2; nf++) {
        acc[mf][nf] = __builtin_amdgcn_mfma_f32_16x16x32_bf16(a_l[mf], b_h[nf], acc[mf][nf], 0, 0, 0);
        acc[mf][nf] = __builtin_amdgcn_mfma_f32_16x16x32_bf16(a_h[mf], b_l[nf], acc[mf][nf], 0, 0, 0);
        acc[mf][nf] = __builtin_amdgcn_mfma_f32_16x16x32_bf16(a_h[mf], b_h[nf], acc[mf][nf], 0, 0, 0);
      }
  }
  #pragma unroll
  for (int nf = 0; nf < 2; nf++) {
    const int col = nt * 64 + nw + nf * 16 + ln;
    const float bv = bias[col];
    #pragma unroll
    for (int mf = 0; mf < 2; mf++) {
      const int row = bm + mw + mf * 16 + lk * 4;
      #pragma unroll
      for (int r = 0; r < 4; r++) {
        float val = acc[mf][nf][r] + bv;
        if (OUTM == 0) {
          Cf[(size_t)(row + r) * HIDC + col] = val;
        } else if (OUTM == 1) {
          unsigned short h16, l16;
          split2(val, h16, l16);
          Chi[(size_t)(row + r) * HIDC + col] = h16;
          Clo[(size_t)(row + r) * HIDC + col] = l16;
        } else {
          Ckm[(size_t)(row + r) * 512 + col] = bf16rne(val);
        }
      }
    }
  }
}

// ================= x pre-split: fp32 -> hi/lo planes (into d_out scratch) =================
__global__ __launch_bounds__(256)
void split_x(const float* __restrict__ x0, const float* __restrict__ x1,
             const float* __restrict__ x2, unsigned short* __restrict__ out) {
  size_t gi = (size_t)blockIdx.x * 2048 + threadIdx.x * 8;
  int t = (int)(gi >> 22);                 // NM = 2^22
  size_t i = gi & (NM - 1);
  const float* x = t == 0 ? x0 : t == 1 ? x1 : x2;
  float4 v0 = *(const float4*)(x + i);
  float4 v1 = *(const float4*)(x + i + 4);
  float xs[8] = {v0.x, v0.y, v0.z, v0.w, v1.x, v1.y, v1.z, v1.w};
  short8 h8, l8;
  #pragma unroll
  for (int j = 0; j < 8; j++) {
    unsigned short h, lo;
    split2(xs[j], h, lo);
    h8[j] = (short)h; l8[j] = (short)lo;
  }
  unsigned short* hp = out + (size_t)t * 2 * NM;
  *(short8*)(hp + i) = h8;
  *(short8*)(hp + NM + i) = l8;
}

// ================= plain-weight prep (slots 0..29) =================
__global__ __launch_bounds__(256)
void prep_plain(const float* __restrict__ Win, const float* __restrict__ Qw,
                const float* __restrict__ Aw, const float* __restrict__ Wout,
                unsigned short* __restrict__ wh, unsigned short* __restrict__ wlo) {
  const int j = blockIdx.y;
  const float* src = j < 3  ? Win  + (size_t)j * 65536 :
                     j < 15 ? Qw   + (size_t)(j - 3) * 65536 :
                     j < 27 ? Aw   + (size_t)(j - 15) * 65536 :
                              Wout + (size_t)(j - 27) * 65536;
  const int c = blockIdx.x;
  const int nt = c >> 3, ks = c & 7;
  const int t = threadIdx.x;
  const int n = nt * 64 + (t & 63);
  const int kq = t >> 6;
  const int k = ks * 32 + kq * 8;
  short8 h8, l8;
  #pragma unroll
  for (int i = 0; i < 8; i++) {
    unsigned short h, lo;
    split2(src[(size_t)(k + i) * HIDC + n], h, lo);
    h8[i] = (short)h; l8[i] = (short)lo;
  }
  size_t off = (size_t)j * 65536 + nt * 16384 + ks * 2048 + kq * 512 + (size_t)(t & 63) * 8;
  *(short8*)&wh[off] = h8;
  *(short8*)&wlo[off] = l8;
}

// ================= fused K/V weight build (slots 30 + lr*2 + kv) =================
__global__ __launch_bounds__(256)
void fuse_kernel(const float* __restrict__ Kw, const float* __restrict__ Kb,
                 const float* __restrict__ Vw, const float* __restrict__ Vb,
                 const float* __restrict__ Arel, const float* __restrict__ Mrel,
                 unsigned short* __restrict__ wh, unsigned short* __restrict__ wlo,
                 float* __restrict__ fb) {
  const int h = blockIdx.x;
  const int lr = blockIdx.y;
  const int kv = blockIdx.z;
  const int l = lr >> 2, r = lr & 3;
  const int s = (r == 0) ? 1 : (r == 2) ? 2 : 0;   // REL src types {1,0,2,0}
  const float* Wsrc = (kv ? Vw : Kw) + (size_t)(l * 3 + s) * 65536;
  const float* bsrc = (kv ? Vb : Kb) + (size_t)(l * 3 + s) * 256;
  const float* A    = (kv ? Mrel : Arel) + (size_t)lr * 8192 + h * 1024;
  const int slot = 30 + lr * 2 + kv;
  float* fbp = fb + (size_t)lr * 512 + kv * 256;
  __shared__ float Am[32][32];
  const int tid = threadIdx.x;
  #pragma unroll
  for (int i = 0; i < 4; i++) { int p = tid + i * 256; Am[p >> 5][p & 31] = A[p]; }
  __syncthreads();
  float w[32];
  #pragma unroll
  for (int d = 0; d < 32; d++) w[d] = Wsrc[(size_t)tid * HIDC + h * 32 + d];
  const size_t sbase = (size_t)slot * 65536;
  #pragma unroll
  for (int e = 0; e < 32; e++) {
    float sacc = 0.0f;
    #pragma unroll
    for (int d = 0; d < 32; d++) sacc += w[d] * Am[d][e];
    unsigned short hi, lo;
    split2(sacc, hi, lo);
    size_t o = sbase + woff(tid, h * 32 + e);
    wh[o] = hi; wlo[o] = lo;
  }
  if (tid < 32) {
    float sacc = 0.0f;
    #pragma unroll
    for (int d = 0; d < 32; d++) sacc += bsrc[h * 32 + d] * Am[d][tid];
    fbp[tid + 0] = 0.0f;   // placeholder overwritten below (keep uniform writes simple)
    fbp[tid] = sacc;
  }
  if (tid >= 32 && tid < 256) {}   // no-op
  if (tid < 256 && tid >= 32) {}
  // fill remaining bias entries (h covers 32 cols; other blocks with different h fill theirs)
  if (tid < 32) {
    // recompute index with head offset
    float sacc = 0.0f;
    #pragma unroll
    for (int d = 0; d < 32; d++) sacc += bsrc[h * 32 + d] * Am[d][tid];
    fbp[h * 32 + tid] = sacc;
  }
}

// ================= per-relation CSR build =================
__global__ __launch_bounds__(256)
void zero_cnt_kernel(int* __restrict__ cnt) {
  cnt[blockIdx.x * 256 + threadIdx.x] = 0;
}

__global__ __launch_bounds__(256)
void count_kernel(const int* __restrict__ e0, const int* __restrict__ e1,
                  const int* __restrict__ e2, const int* __restrict__ e3,
                  int* __restrict__ cnt) {
  int g = blockIdx.x * 256 + threadIdx.x;
  int r = g >> 16, e = g & 0xFFFF;
  const int* ei = (r == 0) ? e0 : (r == 1) ? e1 : (r == 2) ? e2 : e3;
  atomicAdd(&cnt[r * N_NODES + ei[E_EDGES + e]], 1);
}

__global__ __launch_bounds__(256)
void scan_kernel(const int* __restrict__ cnt, int* __restrict__ rp, int* __restrict__ cur) {
  const int r = blockIdx.x;
  const int* c = cnt + r * N_NODES;
  int* rpp = rp + r * (N_NODES + 1);
  int* u = cur + r * N_NODES;
  __shared__ int part[256];
  const int tid = threadIdx.x;
  const int base = tid * 64;
  int s = 0;
  for (int i = 0; i < 64; i++) s += c[base + i];
  part[tid] = s;
  __syncthreads();
  for (int off = 1; off < 256; off <<= 1) {
    int v = (tid >= off) ? part[tid - off] : 0;
    __syncthreads();
    part[tid] += v;
    __syncthreads();
  }
  int run = (tid == 0) ? 0 : part[tid - 1];
  for (int i = 0; i < 64; i++) {
    int idx = base + i;
    rpp[idx] = run;
    u[idx] = run;
    run += c[idx];
  }
  if (tid == 255) rpp[N_NODES] = run;
}

__global__ __launch_bounds__(256)
void fill_kernel(const int* __restrict__ e0, const int* __restrict__ e1,
                 const int* __restrict__ e2, const int* __restrict__ e3,
                 int* __restrict__ cur, int* __restrict__ srcl) {
  int g = blockIdx.x * 256 + threadIdx.x;
  int r = g >> 16, e = g & 0xFFFF;
  const int* ei = (r == 0) ? e0 : (r == 1) ? e1 : (r == 2) ? e2 : e3;
  int pos = atomicAdd(&cur[r * N_NODES + ei[E_EDGES + e]], 1);
  srcl[r * E_EDGES + pos] = ei[e];
}

// ================= single-pass attention per dst type (1-2 relations) =================
// one wave per dst node; lane l: head h=l>>3, dims l*4..l*4+3.
// km layout: bf16, node*512 + kv*256 + dim. Epilogue: gelu + split -> hi/lo planes.
__global__ __launch_bounds__(256)
void attn_ps(const float* __restrict__ q,
             const unsigned short* __restrict__ km0, const float* __restrict__ pr0,
             const int* __restrict__ rp0, const int* __restrict__ sl0,
             const unsigned short* __restrict__ km1, const float* __restrict__ pr1,
             const int* __restrict__ rp1, const int* __restrict__ sl1,
             int two, unsigned short* __restrict__ oh, unsigned short* __restrict__ ol) {
  const int n = (blockIdx.x * 256 + threadIdx.x) >> 6;
  const int lane = threadIdx.x & 63;
  const int h = lane >> 3;
  const float scale = 0.17677669529663687f;   // 1/sqrt(32)
  float4 qv = *(const float4*)(q + (size_t)n * HIDC + lane * 4);
  float m = -INFINITY, den = 0.0f;
  float ax = 0.f, ay = 0.f, az = 0.f, aw = 0.f;

  auto run = [&](const unsigned short* km, float p, const int* rp, const int* sl) {
    const int beg = rp[n], end = rp[n + 1];
    for (int i = beg; i < end; i++) {
      int src = sl[i];
      const unsigned short* base = km + (size_t)src * 512 + lane * 4;
      uint2 uk = *(const uint2*)base;
      uint2 um = *(const uint2*)(base + 256);
      float k0 = __uint_as_float(uk.x << 16), k1 = __uint_as_float(uk.x & 0xFFFF0000u);
      float k2 = __uint_as_float(uk.y << 16), k3 = __uint_as_float(uk.y & 0xFFFF0000u);
      float dot = qv.x * k0 + qv.y * k1 + qv.z * k2 + qv.w * k3;
      dot += __shfl_xor(dot, 1);
      dot += __shfl_xor(dot, 2);
      dot += __shfl_xor(dot, 4);
      float s = dot * p;
      float mn = fmaxf(m, s);
      float c = expf(m - mn);
      float wgt = expf(s - mn);
      den = den * c + wgt;
      float m0 = __uint_as_float(um.x << 16), m1 = __uint_as_float(um.x & 0xFFFF0000u);
      float m2 = __uint_as_float(um.y << 16), m3 = __uint_as_float(um.y & 0xFFFF0000u);
      ax = ax * c + wgt * m0;
      ay = ay * c + wgt * m1;
      az = az * c + wgt * m2;
      aw = aw * c + wgt * m3;
      m = mn;
    }
  };
  run(km0, pr0[h] * scale, rp0, sl0);
  if (two) run(km1, pr1[h] * scale, rp1, sl1);

  float inv = 1.0f / fmaxf(den, 1e-16f);
  float vals[4] = {ax * inv, ay * inv, az * inv, aw * inv};
  unsigned hi01, hi23, lo01, lo23;
  unsigned short hh[4], ll[4];
  #pragma unroll
  for (int j = 0; j < 4; j++) split2(gelu_f(vals[j]), hh[j], ll[j]);
  hi01 = (unsigned)hh[0] | ((unsigned)hh[1] << 16);
  hi23 = (unsigned)hh[2] | ((unsigned)hh[3] << 16);
  lo01 = (unsigned)ll[0] | ((unsigned)ll[1] << 16);
  lo23 = (unsigned)ll[2] | ((unsigned)ll[3] << 16);
  size_t o = (size_t)n * HIDC + lane * 4;
  *(uint2*)(oh + o) = make_uint2(hi01, hi23);
  *(uint2*)(ol + o) = make_uint2(lo01, lo23);
}

// ================= skip-gate + residual + LayerNorm on hi/lo planes =================
__global__ __launch_bounds__(256)
void ln_ps(const float* __restrict__ ob, unsigned short* __restrict__ hH,
           unsigned short* __restrict__ hL, const float* __restrict__ skipv,
           const float* __restrict__ g, const float* __restrict__ b) {
  const int row = blockIdx.x, tid = threadIdx.x;
  float a = 1.0f / (1.0f + expf(-skipv[0]));
  size_t off = (size_t)row * HIDC + tid;
  float hv = bf2f(hH[off]) + bf2f(hL[off]);
  float ov = ob[off];
  float y = a * ov + (1.0f - a) * hv + hv;
  __shared__ float red[256];
  red[tid] = y;
  __syncthreads();
  #pragma unroll
  for (int o = 128; o > 0; o >>= 1) {
    if (tid < o) red[tid] += red[tid + o];
    __syncthreads();
  }
  float mu = red[0] * (1.0f / 256.0f);
  __syncthreads();
  float dv = y - mu;
  red[tid] = dv * dv;
  __syncthreads();
  #pragma unroll
  for (int o = 128; o > 0; o >>= 1) {
    if (tid < o) red[tid] += red[tid + o];
    __syncthreads();
  }
  float var = red[0] * (1.0f / 256.0f);
  float rs = 1.0f / sqrtf(var + 1e-5f);
  float out = dv * rs * g[tid] + b[tid];
  unsigned short h16, l16;
  split2(out, h16, l16);
  hH[off] = h16;
  hL[off] = l16;
}

extern "C" void kernel_launch(void* const* d_in, const int* in_sizes, int n_in,
                              void* d_out, int out_size, void* d_ws, size_t ws_size,
                              hipStream_t stream) {
  const float* x0 = (const float*)d_in[0];
  const float* x1 = (const float*)d_in[1];
  const float* x2 = (const float*)d_in[2];
  const int* ei[4] = {(const int*)d_in[3], (const int*)d_in[4], (const int*)d_in[5], (const int*)d_in[6]};
  const float* Win  = (const float*)d_in[7];
  const float* b_in = (const float*)d_in[8];
  const float* Kw   = (const float*)d_in[9];
  const float* Kb   = (const float*)d_in[10];
  const float* Qw   = (const float*)d_in[11];
  const float* Qb   = (const float*)d_in[12];
  const float* Vw   = (const float*)d_in[13];
  const float* Vb   = (const float*)d_in[14];
  const float* Arel = (const float*)d_in[15];
  const float* Mrel = (const float*)d_in[16];
  const float* Prel = (const float*)d_in[17];
  const float* Aw   = (const float*)d_in[18];
  const float* Ab   = (const float*)d_in[19];
  const float* skip = (const float*)d_in[20];
  const float* ln_g = (const float*)d_in[21];
  const float* ln_b = (const float*)d_in[22];
  const float* Wout = (const float*)d_in[23];
  const float* b_out= (const float*)d_in[24];

  // ---- workspace (~112 MB) ----
  float* f = (float*)d_ws;
  unsigned short* hsP = (unsigned short*)f;            // 3 types x 2NM ushorts (hi|lo)
  float* qb = f + 3 * NM;                              // fp32 q / gelu-GEMM out
  unsigned short* kmr = (unsigned short*)(f + 4 * NM); // 2 buffers x 16384*512 ushorts
  unsigned short* wprep = (unsigned short*)(f + 6 * NM); // 2 planes x PLANEU
  float* fb = (float*)(wprep + 2 * PLANEU);            // 16 lr x 512
  int* ib = (int*)(fb + 8192);
  int* cnt  = ib;
  int* rp   = ib + 4 * N_NODES;
  int* cur  = rp + 4 * (N_NODES + 1);
  int* srcl = cur + 4 * N_NODES;

  // d_out scratch: per type t, hi plane at t*2NM, lo at t*2NM+NM (x-presplit, later gelu planes)
  unsigned short* gp = (unsigned short*)d_out;

  auto hsH = [&](int t) { return hsP + (size_t)t * 2 * NM; };
  auto hsL = [&](int t) { return hsP + (size_t)t * 2 * NM + NM; };
  auto gpH = [&](int t) { return gp + (size_t)t * 2 * NM; };
  auto gpL = [&](int t) { return gp + (size_t)t * 2 * NM + NM; };
  auto kmb = [&](int b) { return kmr + (size_t)b * N_NODES * 512; };
  auto wH = [&](int slot) { return wprep + (size_t)slot * 65536; };
  auto wL = [&](int slot) { return wprep + PLANEU + (size_t)slot * 65536; };

  const dim3 g256(4, 256), g512(8, 256);

  // weight prep + x pre-split + CSR (every call; ws/d_out re-poisoned)
  prep_plain<<<dim3(32, 30), 256, 0, stream>>>(Win, Qw, Aw, Wout, wprep, wprep + PLANEU);
  fuse_kernel<<<dim3(8, 16, 2), 256, 0, stream>>>(Kw, Kb, Vw, Vb, Arel, Mrel,
                                                  wprep, wprep + PLANEU, fb);
  split_x<<<3 * NM / 2048, 256, 0, stream>>>(x0, x1, x2, gp);
  zero_cnt_kernel<<<4 * N_NODES / 256, 256, 0, stream>>>(cnt);
  count_kernel<<<4 * E_EDGES / 256, 256, 0, stream>>>(ei[0], ei[1], ei[2], ei[3], cnt);
  scan_kernel<<<4, 256, 0, stream>>>(cnt, rp, cur);
  fill_kernel<<<4 * E_EDGES / 256, 256, 0, stream>>>(ei[0], ei[1], ei[2], ei[3], cur, srcl);

  // input projections: x planes -> hs planes
  for (int t = 0; t < 3; t++)
    gemm_ps<1><<<g256, 256, 0, stream>>>(gpH(t), gpL(t), wH(t), wL(t), b_in + t * 256,
                                         nullptr, hsH(t), hsL(t), nullptr);

  // per-layer: dst groups {r0,r3}->t0, {r2}->t1, {r1}->t2 ; SRC = {1,0,2,0}
  for (int l = 0; l < 4; l++) {
    const int lr0 = l * 4 + 0, lr1 = l * 4 + 1, lr2 = l * 4 + 2, lr3 = l * 4 + 3;

    // dst type 0: relations r0 (src 1) + r3 (src 0)
    gemm_ps<0><<<g256, 256, 0, stream>>>(hsH(0), hsL(0), wH(3 + l * 3 + 0), wL(3 + l * 3 + 0),
                                         Qb + (l * 3 + 0) * 256, qb, nullptr, nullptr, nullptr);
    gemm_ps<2><<<g512, 256, 0, stream>>>(hsH(1), hsL(1), wH(30 + lr0 * 2), wL(30 + lr0 * 2),
                                         fb + lr0 * 512, nullptr, nullptr, nullptr, kmb(0));
    gemm_ps<2><<<g512, 256, 0, stream>>>(hsH(0), hsL(0), wH(30 + lr3 * 2), wL(30 + lr3 * 2),
                                         fb + lr3 * 512, nullptr, nullptr, nullptr, kmb(1));
    attn_ps<<<N_NODES / 4, 256, 0, stream>>>(qb,
        kmb(0), Prel + lr0 * 8, rp + 0 * (N_NODES + 1), srcl + 0 * E_EDGES,
        kmb(1), Prel + lr3 * 8, rp + 3 * (N_NODES + 1), srcl + 3 * E_EDGES,
        1, gpH(0), gpL(0));

    // dst type 1: relation r2 (src 2)
    gemm_ps<0><<<g256, 256, 0, stream>>>(hsH(1), hsL(1), wH(3 + l * 3 + 1), wL(3 + l * 3 + 1),
                                         Qb + (l * 3 + 1) * 256, qb, nullptr, nullptr, nullptr);
    gemm_ps<2><<<g512, 256, 0, stream>>>(hsH(2), hsL(2), wH(30 + lr2 * 2), wL(30 + lr2 * 2),
                                         fb + lr2 * 512, nullptr, nullptr, nullptr, kmb(0));
    attn_ps<<<N_NODES / 4, 256, 0, stream>>>(qb,
        kmb(0), Prel + lr2 * 8, rp + 2 * (N_NODES + 1), srcl + 2 * E_EDGES,
        kmb(0), Prel + lr2 * 8, rp + 2 * (N_NODES + 1), srcl + 2 * E_EDGES,
        0, gpH(1), gpL(1));

    // dst type 2: relation r1 (src 0)
    gemm_ps<0><<<g256, 256, 0, stream>>>(hsH(2), hsL(2), wH(3 + l * 3 + 2), wL(3 + l * 3 + 2),
                                         Qb + (l * 3 + 2) * 256, qb, nullptr, nullptr, nullptr);
    gemm_ps<2><<<g512, 256, 0, stream>>>(hsH(0), hsL(0), wH(30 + lr1 * 2), wL(30 + lr1 * 2),
                                         fb + lr1 * 512, nullptr, nullptr, nullptr, kmb(0));
    attn_ps<<<N_NODES / 4, 256, 0, stream>>>(qb,
        kmb(0), Prel + lr1 * 8, rp + 1 * (N_NODES + 1), srcl + 1 * E_EDGES,
        kmb(0), Prel + lr1 * 8, rp + 1 * (N_NODES + 1), srcl + 1 * E_EDGES,
        0, gpH(2), gpL(2));

    // epilogue: gelu-planes @ Aw + Ab -> qb ; skip-gate+residual+LN on hs planes
    for (int t = 0; t < 3; t++) {
      size_t bo = (size_t)(l * 3 + t) * 256;
      gemm_ps<0><<<g256, 256, 0, stream>>>(gpH(t), gpL(t), wH(15 + l * 3 + t), wL(15 + l * 3 + t),
                                           Ab + bo, qb, nullptr, nullptr, nullptr);
      ln_ps<<<N_NODES, 256, 0, stream>>>(qb, hsH(t), hsL(t), skip + l * 3 + t,
                                         ln_g + bo, ln_b + bo);
    }
  }

  // output projections (fp32) into d_out
  for (int t = 0; t < 3; t++)
    gemm_ps<0><<<g256, 256, 0, stream>>>(hsH(t), hsL(t), wH(27 + t), wL(27 + t),
                                         b_out + t * 256, (float*)d_out + t * NM,
                                         nullptr, nullptr, nullptr);
}

// Round 6
// 1364.945 us; speedup vs baseline: 2.7418x; 1.3446x over previous
//
#include <hip/hip_runtime.h>

#define N_NODES 16384
#define E_EDGES 65536
#define HIDC 256
#define NM ((size_t)N_NODES * HIDC)       // 4194304
#define NSLOT 62
#define PLANEU ((size_t)NSLOT * 65536)    // ushorts per wprep plane
#define KMU ((size_t)N_NODES * 512)       // ushorts per km buffer

typedef __attribute__((ext_vector_type(8))) short short8;
typedef __attribute__((ext_vector_type(4))) float f32x4;

__device__ __forceinline__ float gelu_f(float x) {
  return 0.5f * x * (1.0f + tanhf(0.7978845608028654f * (x + 0.044715f * x * x * x)));
}
__device__ __forceinline__ unsigned short bf16rne(float x) {
  unsigned u = __float_as_uint(x);
  return (unsigned short)((u + 0x7FFFu + ((u >> 16) & 1u)) >> 16);
}
__device__ __forceinline__ void split2(float x, unsigned short& h, unsigned short& l) {
  h = bf16rne(x);
  float rem = x - __uint_as_float(((unsigned)h) << 16);
  l = bf16rne(rem);
}
__device__ __forceinline__ float bf2f(unsigned short v) {
  return __uint_as_float(((unsigned)v) << 16);
}
__device__ __forceinline__ int src_of(int r) { return (r == 0) ? 1 : (r == 2) ? 2 : 0; }
// wprep element offset within a slot: [nt(4)][ks(8)][kq(4)][n(64)][i(8)]
__device__ __forceinline__ size_t woff(int k, int n) {
  return (size_t)(((n >> 6) & 3) * 16384 + (k >> 5) * 2048 + (((k >> 3) & 3) * 512) + ((n & 63) * 8) + (k & 7));
}

// ---------------- shared GEMM core: 64x64 tile, K=256, split-bf16 3-MFMA ----------------
__device__ __forceinline__ void gemm_core(const unsigned short* __restrict__ Ahi,
                                          const unsigned short* __restrict__ Alo,
                                          const unsigned short* __restrict__ Whi,
                                          const unsigned short* __restrict__ Wlo,
                                          int bm, int ntt, f32x4 (&acc)[2][2]) {
  __shared__ short Ah[2048], Al[2048], Bh[2048], Bl[2048];
  const int tid = threadIdx.x;
  const int w = tid >> 6, l = tid & 63;
  const int mw = (w >> 1) * 32, nw = (w & 1) * 32;
  const int lk = l >> 4, ln = l & 15;
  const int sm = tid & 63, skq = tid >> 6;
  for (int ks = 0; ks < 8; ks++) {
    const size_t aoff = (size_t)(bm + sm) * HIDC + ks * 32 + skq * 8;
    short8 ah = *(const short8*)(Ahi + aoff);
    short8 al = *(const short8*)(Alo + aoff);
    const size_t wo = (size_t)ntt * 16384 + ks * 2048 + tid * 8;
    short8 wh = *(const short8*)(Whi + wo);
    short8 wl = *(const short8*)(Wlo + wo);
    if (ks) __syncthreads();
    *(short8*)&Ah[tid * 8] = ah;
    *(short8*)&Al[tid * 8] = al;
    *(short8*)&Bh[tid * 8] = wh;
    *(short8*)&Bl[tid * 8] = wl;
    __syncthreads();
    short8 a_h[2], a_l[2], b_h[2], b_l[2];
    #pragma unroll
    for (int mf = 0; mf < 2; mf++) {
      int idx = (lk * 64 + mw + mf * 16 + ln) * 8;
      a_h[mf] = *(const short8*)&Ah[idx];
      a_l[mf] = *(const short8*)&Al[idx];
    }
    #pragma unroll
    for (int nf = 0; nf < 2; nf++) {
      int idx = (lk * 64 + nw + nf * 16 + ln) * 8;
      b_h[nf] = *(const short8*)&Bh[idx];
      b_l[nf] = *(const short8*)&Bl[idx];
    }
    #pragma unroll
    for (int mf = 0; mf < 2; mf++)
      #pragma unroll
      for (int nf = 0; nf < 2; nf++) {
        acc[mf][nf] = __builtin_amdgcn_mfma_f32_16x16x32_bf16(a_l[mf], b_h[nf], acc[mf][nf], 0, 0, 0);
        acc[mf][nf] = __builtin_amdgcn_mfma_f32_16x16x32_bf16(a_h[mf], b_l[nf], acc[mf][nf], 0, 0, 0);
        acc[mf][nf] = __builtin_amdgcn_mfma_f32_16x16x32_bf16(a_h[mf], b_h[nf], acc[mf][nf], 0, 0, 0);
      }
  }
}

// ---------------- batched per-layer GEMM: 3 Q jobs + 4 K|V double-wide jobs ----------------
// grid (256, 44): y<12 -> Q (t=y>>2, ntt=y&3); y>=12 -> KV (r=(y-12)>>3, nt8=(y-12)&7)
__global__ __launch_bounds__(256)
void gemm_layer(int l, const unsigned short* __restrict__ wprep,
                const unsigned short* __restrict__ hsP,
                const float* __restrict__ Qb, const float* __restrict__ fb,
                float* __restrict__ qb3, unsigned short* __restrict__ km) {
  const int y = blockIdx.y;
  const int bm = blockIdx.x * 64;
  const int tid = threadIdx.x;
  const int w = tid >> 6, lx = tid & 63;
  const int mw = (w >> 1) * 32, nw = (w & 1) * 32;
  const int lk = lx >> 4, ln = lx & 15;
  f32x4 acc[2][2];
  #pragma unroll
  for (int a = 0; a < 2; a++)
    #pragma unroll
    for (int b = 0; b < 2; b++) acc[a][b] = f32x4{0.f, 0.f, 0.f, 0.f};

  if (y < 12) {
    const int t = y >> 2, ntt = y & 3;
    const int slot = 3 + l * 3 + t;
    const unsigned short* Ah_ = hsP + (size_t)t * 2 * NM;
    gemm_core(Ah_, Ah_ + NM, wprep + (size_t)slot * 65536, wprep + PLANEU + (size_t)slot * 65536,
              bm, ntt, acc);
    const float* bias = Qb + (l * 3 + t) * 256;
    float* out = qb3 + (size_t)t * NM;
    #pragma unroll
    for (int nf = 0; nf < 2; nf++) {
      const int col = ntt * 64 + nw + nf * 16 + ln;
      const float bv = bias[col];
      #pragma unroll
      for (int mf = 0; mf < 2; mf++) {
        const int row = bm + mw + mf * 16 + lk * 4;
        #pragma unroll
        for (int r4 = 0; r4 < 4; r4++)
          out[(size_t)(row + r4) * HIDC + col] = acc[mf][nf][r4] + bv;
      }
    }
  } else {
    const int y2 = y - 12;
    const int r = y2 >> 3, nt8 = y2 & 7;
    const int lr = l * 4 + r;
    const int s = src_of(r);
    const int slot = 30 + lr * 2 + (nt8 >> 2);
    const int ntt = nt8 & 3;
    const unsigned short* Ah_ = hsP + (size_t)s * 2 * NM;
    gemm_core(Ah_, Ah_ + NM, wprep + (size_t)slot * 65536, wprep + PLANEU + (size_t)slot * 65536,
              bm, ntt, acc);
    unsigned short* kmr = km + (size_t)r * KMU;
    #pragma unroll
    for (int nf = 0; nf < 2; nf++) {
      const int c512 = nt8 * 64 + nw + nf * 16 + ln;
      const float bv = fb[lr * 512 + c512];
      #pragma unroll
      for (int mf = 0; mf < 2; mf++) {
        const int row = bm + mw + mf * 16 + lk * 4;
        #pragma unroll
        for (int r4 = 0; r4 < 4; r4++)
          kmr[(size_t)(row + r4) * 512 + c512] = bf16rne(acc[mf][nf][r4] + bv);
      }
    }
  }
}

// ---------------- batched 3-type GEMM (input proj / gelu / out proj) ----------------
// grid (256, 12): t=y>>2, ntt=y&3. OUTM: 0 = fp32 out (+t*NM), 1 = hi/lo planes (+t*2NM)
template<int OUTM>
__global__ __launch_bounds__(256)
void gemm3(const unsigned short* __restrict__ Abase, const unsigned short* __restrict__ wprep,
           int slot0, const float* __restrict__ bias0,
           float* __restrict__ outf, unsigned short* __restrict__ outP) {
  const int y = blockIdx.y;
  const int t = y >> 2, ntt = y & 3;
  const int bm = blockIdx.x * 64;
  const int tid = threadIdx.x;
  const int w = tid >> 6, lx = tid & 63;
  const int mw = (w >> 1) * 32, nw = (w & 1) * 32;
  const int lk = lx >> 4, ln = lx & 15;
  f32x4 acc[2][2];
  #pragma unroll
  for (int a = 0; a < 2; a++)
    #pragma unroll
    for (int b = 0; b < 2; b++) acc[a][b] = f32x4{0.f, 0.f, 0.f, 0.f};
  const unsigned short* Ah_ = Abase + (size_t)t * 2 * NM;
  const int slot = slot0 + t;
  gemm_core(Ah_, Ah_ + NM, wprep + (size_t)slot * 65536, wprep + PLANEU + (size_t)slot * 65536,
            bm, ntt, acc);
  const float* bias = bias0 + t * 256;
  #pragma unroll
  for (int nf = 0; nf < 2; nf++) {
    const int col = ntt * 64 + nw + nf * 16 + ln;
    const float bv = bias[col];
    #pragma unroll
    for (int mf = 0; mf < 2; mf++) {
      const int row = bm + mw + mf * 16 + lk * 4;
      #pragma unroll
      for (int r4 = 0; r4 < 4; r4++) {
        float val = acc[mf][nf][r4] + bv;
        size_t off = (size_t)(row + r4) * HIDC + col;
        if (OUTM == 0) {
          outf[(size_t)t * NM + off] = val;
        } else {
          unsigned short h16, l16;
          split2(val, h16, l16);
          outP[(size_t)t * 2 * NM + off] = h16;
          outP[(size_t)t * 2 * NM + NM + off] = l16;
        }
      }
    }
  }
}

// ---------------- x pre-split ----------------
__global__ __launch_bounds__(256)
void split_x(const float* __restrict__ x0, const float* __restrict__ x1,
             const float* __restrict__ x2, unsigned short* __restrict__ out) {
  size_t gi = (size_t)blockIdx.x * 2048 + threadIdx.x * 8;
  int t = (int)(gi >> 22);
  size_t i = gi & (NM - 1);
  const float* x = t == 0 ? x0 : t == 1 ? x1 : x2;
  float4 v0 = *(const float4*)(x + i);
  float4 v1 = *(const float4*)(x + i + 4);
  float xs[8] = {v0.x, v0.y, v0.z, v0.w, v1.x, v1.y, v1.z, v1.w};
  short8 h8, l8;
  #pragma unroll
  for (int j = 0; j < 8; j++) {
    unsigned short h, lo;
    split2(xs[j], h, lo);
    h8[j] = (short)h; l8[j] = (short)lo;
  }
  unsigned short* hp = out + (size_t)t * 2 * NM;
  *(short8*)(hp + i) = h8;
  *(short8*)(hp + NM + i) = l8;
}

// ---------------- plain-weight prep (slots 0..29) ----------------
__global__ __launch_bounds__(256)
void prep_plain(const float* __restrict__ Win, const float* __restrict__ Qw,
                const float* __restrict__ Aw, const float* __restrict__ Wout,
                unsigned short* __restrict__ wh, unsigned short* __restrict__ wlo) {
  const int j = blockIdx.y;
  const float* src = j < 3  ? Win  + (size_t)j * 65536 :
                     j < 15 ? Qw   + (size_t)(j - 3) * 65536 :
                     j < 27 ? Aw   + (size_t)(j - 15) * 65536 :
                              Wout + (size_t)(j - 27) * 65536;
  const int c = blockIdx.x;
  const int nt = c >> 3, ks = c & 7;
  const int t = threadIdx.x;
  const int n = nt * 64 + (t & 63);
  const int kq = t >> 6;
  const int k = ks * 32 + kq * 8;
  short8 h8, l8;
  #pragma unroll
  for (int i = 0; i < 8; i++) {
    unsigned short h, lo;
    split2(src[(size_t)(k + i) * HIDC + n], h, lo);
    h8[i] = (short)h; l8[i] = (short)lo;
  }
  size_t off = (size_t)j * 65536 + nt * 16384 + ks * 2048 + kq * 512 + (size_t)(t & 63) * 8;
  *(short8*)&wh[off] = h8;
  *(short8*)&wlo[off] = l8;
}

// ---------------- fused K/V weight build (slots 30 + lr*2 + kv) ----------------
__global__ __launch_bounds__(256)
void fuse_kernel(const float* __restrict__ Kw, const float* __restrict__ Kb,
                 const float* __restrict__ Vw, const float* __restrict__ Vb,
                 const float* __restrict__ Arel, const float* __restrict__ Mrel,
                 unsigned short* __restrict__ wh, unsigned short* __restrict__ wlo,
                 float* __restrict__ fb) {
  const int h = blockIdx.x;
  const int lr = blockIdx.y;
  const int kv = blockIdx.z;
  const int l = lr >> 2, r = lr & 3;
  const int s = src_of(r);
  const float* Wsrc = (kv ? Vw : Kw) + (size_t)(l * 3 + s) * 65536;
  const float* bsrc = (kv ? Vb : Kb) + (size_t)(l * 3 + s) * 256;
  const float* A    = (kv ? Mrel : Arel) + (size_t)lr * 8192 + h * 1024;
  const int slot = 30 + lr * 2 + kv;
  float* fbp = fb + (size_t)lr * 512 + kv * 256;
  __shared__ float Am[32][32];
  const int tid = threadIdx.x;
  #pragma unroll
  for (int i = 0; i < 4; i++) { int p = tid + i * 256; Am[p >> 5][p & 31] = A[p]; }
  __syncthreads();
  float wv[32];
  #pragma unroll
  for (int d = 0; d < 32; d++) wv[d] = Wsrc[(size_t)tid * HIDC + h * 32 + d];
  const size_t sbase = (size_t)slot * 65536;
  #pragma unroll
  for (int e = 0; e < 32; e++) {
    float sacc = 0.0f;
    #pragma unroll
    for (int d = 0; d < 32; d++) sacc += wv[d] * Am[d][e];
    unsigned short hi, lo;
    split2(sacc, hi, lo);
    size_t o = sbase + woff(tid, h * 32 + e);
    wh[o] = hi; wlo[o] = lo;
  }
  if (tid < 32) {   // bias cols for this head only (race fixed)
    float sacc = 0.0f;
    #pragma unroll
    for (int d = 0; d < 32; d++) sacc += bsrc[h * 32 + d] * Am[d][tid];
    fbp[h * 32 + tid] = sacc;
  }
}

// ---------------- per-relation CSR build ----------------
__global__ __launch_bounds__(256)
void zero_cnt_kernel(int* __restrict__ cnt) {
  cnt[blockIdx.x * 256 + threadIdx.x] = 0;
}
__global__ __launch_bounds__(256)
void count_kernel(const int* __restrict__ e0, const int* __restrict__ e1,
                  const int* __restrict__ e2, const int* __restrict__ e3,
                  int* __restrict__ cnt) {
  int g = blockIdx.x * 256 + threadIdx.x;
  int r = g >> 16, e = g & 0xFFFF;
  const int* ei = (r == 0) ? e0 : (r == 1) ? e1 : (r == 2) ? e2 : e3;
  atomicAdd(&cnt[r * N_NODES + ei[E_EDGES + e]], 1);
}
__global__ __launch_bounds__(256)
void scan_kernel(const int* __restrict__ cnt, int* __restrict__ rp, int* __restrict__ cur) {
  const int r = blockIdx.x;
  const int* c = cnt + r * N_NODES;
  int* rpp = rp + r * (N_NODES + 1);
  int* u = cur + r * N_NODES;
  __shared__ int part[256];
  const int tid = threadIdx.x;
  const int base = tid * 64;
  int s = 0;
  for (int i = 0; i < 64; i++) s += c[base + i];
  part[tid] = s;
  __syncthreads();
  for (int off = 1; off < 256; off <<= 1) {
    int v = (tid >= off) ? part[tid - off] : 0;
    __syncthreads();
    part[tid] += v;
    __syncthreads();
  }
  int run = (tid == 0) ? 0 : part[tid - 1];
  for (int i = 0; i < 64; i++) {
    int idx = base + i;
    rpp[idx] = run;
    u[idx] = run;
    run += c[idx];
  }
  if (tid == 255) rpp[N_NODES] = run;
}
__global__ __launch_bounds__(256)
void fill_kernel(const int* __restrict__ e0, const int* __restrict__ e1,
                 const int* __restrict__ e2, const int* __restrict__ e3,
                 int* __restrict__ cur, int* __restrict__ srcl) {
  int g = blockIdx.x * 256 + threadIdx.x;
  int r = g >> 16, e = g & 0xFFFF;
  const int* ei = (r == 0) ? e0 : (r == 1) ? e1 : (r == 2) ? e2 : e3;
  int pos = atomicAdd(&cur[r * N_NODES + ei[E_EDGES + e]], 1);
  srcl[r * E_EDGES + pos] = ei[e];
}

// ---------------- batched attention: all 3 dst types, online softmax ----------------
// grid 3*4096 blocks; t = b>>12; node = (b&4095)*4 + wave. Epilogue: gelu + split.
__global__ __launch_bounds__(256)
void attn_layer(int l, const float* __restrict__ qb3, const unsigned short* __restrict__ km,
                const float* __restrict__ Prel, const int* __restrict__ rp,
                const int* __restrict__ srcl, unsigned short* __restrict__ gp) {
  const int b = blockIdx.x;
  const int t = b >> 12;
  const int n = ((b & 4095) << 2) + (threadIdx.x >> 6);
  const int lane = threadIdx.x & 63;
  const int h = lane >> 3;
  const float scale = 0.17677669529663687f;   // 1/sqrt(32)
  const float* q = qb3 + (size_t)t * NM;
  float4 qv = *(const float4*)(q + (size_t)n * HIDC + lane * 4);
  float m = -INFINITY, den = 0.0f;
  float ax = 0.f, ay = 0.f, az = 0.f, aw = 0.f;

  auto run = [&](int r) {
    const unsigned short* kmr = km + (size_t)r * KMU;
    const float p = Prel[(l * 4 + r) * 8 + h] * scale;
    const int* rpp = rp + r * (N_NODES + 1);
    const int* sl = srcl + r * E_EDGES;
    const int beg = rpp[n], end = rpp[n + 1];
    for (int i = beg; i < end; i++) {
      int src = sl[i];
      const unsigned short* base = kmr + (size_t)src * 512 + lane * 4;
      uint2 uk = *(const uint2*)base;
      uint2 um = *(const uint2*)(base + 256);
      float k0 = __uint_as_float(uk.x << 16), k1 = __uint_as_float(uk.x & 0xFFFF0000u);
      float k2 = __uint_as_float(uk.y << 16), k3 = __uint_as_float(uk.y & 0xFFFF0000u);
      float dot = qv.x * k0 + qv.y * k1 + qv.z * k2 + qv.w * k3;
      dot += __shfl_xor(dot, 1);
      dot += __shfl_xor(dot, 2);
      dot += __shfl_xor(dot, 4);
      float s = dot * p;
      float mn = fmaxf(m, s);
      float c = expf(m - mn);
      float wgt = expf(s - mn);
      den = den * c + wgt;
      float m0 = __uint_as_float(um.x << 16), m1 = __uint_as_float(um.x & 0xFFFF0000u);
      float m2 = __uint_as_float(um.y << 16), m3 = __uint_as_float(um.y & 0xFFFF0000u);
      ax = ax * c + wgt * m0;
      ay = ay * c + wgt * m1;
      az = az * c + wgt * m2;
      aw = aw * c + wgt * m3;
      m = mn;
    }
  };
  if (t == 0) { run(0); run(3); }
  else if (t == 1) { run(2); }
  else { run(1); }

  float inv = 1.0f / fmaxf(den, 1e-16f);
  float vals[4] = {ax * inv, ay * inv, az * inv, aw * inv};
  unsigned short hh[4], ll[4];
  #pragma unroll
  for (int j = 0; j < 4; j++) split2(gelu_f(vals[j]), hh[j], ll[j]);
  unsigned hi01 = (unsigned)hh[0] | ((unsigned)hh[1] << 16);
  unsigned hi23 = (unsigned)hh[2] | ((unsigned)hh[3] << 16);
  unsigned lo01 = (unsigned)ll[0] | ((unsigned)ll[1] << 16);
  unsigned lo23 = (unsigned)ll[2] | ((unsigned)ll[3] << 16);
  unsigned short* oh = gp + (size_t)t * 2 * NM;
  size_t o = (size_t)n * HIDC + lane * 4;
  *(uint2*)(oh + o) = make_uint2(hi01, hi23);
  *(uint2*)(oh + NM + o) = make_uint2(lo01, lo23);
}

// ---------------- batched LN: skip-gate + residual + LayerNorm on hi/lo planes ----------------
__global__ __launch_bounds__(256)
void ln_layer(int l, const float* __restrict__ qb3, unsigned short* __restrict__ hsP,
              const float* __restrict__ skipA, const float* __restrict__ ln_g,
              const float* __restrict__ ln_b) {
  const int row = blockIdx.x;
  const int t = row >> 14;
  const int rr = row & 16383;
  const int tid = threadIdx.x;
  const int lt = l * 3 + t;
  float a = 1.0f / (1.0f + expf(-skipA[lt]));
  unsigned short* hH = hsP + (size_t)t * 2 * NM;
  unsigned short* hL = hH + NM;
  size_t off = (size_t)rr * HIDC + tid;
  float hv = bf2f(hH[off]) + bf2f(hL[off]);
  float ov = qb3[(size_t)t * NM + off];
  float y = a * ov + (1.0f - a) * hv + hv;
  __shared__ float red[256];
  red[tid] = y;
  __syncthreads();
  #pragma unroll
  for (int o = 128; o > 0; o >>= 1) {
    if (tid < o) red[tid] += red[tid + o];
    __syncthreads();
  }
  float mu = red[0] * (1.0f / 256.0f);
  __syncthreads();
  float dv = y - mu;
  red[tid] = dv * dv;
  __syncthreads();
  #pragma unroll
  for (int o = 128; o > 0; o >>= 1) {
    if (tid < o) red[tid] += red[tid + o];
    __syncthreads();
  }
  float var = red[0] * (1.0f / 256.0f);
  float rs = 1.0f / sqrtf(var + 1e-5f);
  float out = dv * rs * ln_g[lt * 256 + tid] + ln_b[lt * 256 + tid];
  unsigned short h16, l16;
  split2(out, h16, l16);
  hH[off] = h16;
  hL[off] = l16;
}

extern "C" void kernel_launch(void* const* d_in, const int* in_sizes, int n_in,
                              void* d_out, int out_size, void* d_ws, size_t ws_size,
                              hipStream_t stream) {
  const float* x0 = (const float*)d_in[0];
  const float* x1 = (const float*)d_in[1];
  const float* x2 = (const float*)d_in[2];
  const int* ei[4] = {(const int*)d_in[3], (const int*)d_in[4], (const int*)d_in[5], (const int*)d_in[6]};
  const float* Win  = (const float*)d_in[7];
  const float* b_in = (const float*)d_in[8];
  const float* Kw   = (const float*)d_in[9];
  const float* Kb   = (const float*)d_in[10];
  const float* Qw   = (const float*)d_in[11];
  const float* Qb   = (const float*)d_in[12];
  const float* Vw   = (const float*)d_in[13];
  const float* Vb   = (const float*)d_in[14];
  const float* Arel = (const float*)d_in[15];
  const float* Mrel = (const float*)d_in[16];
  const float* Prel = (const float*)d_in[17];
  const float* Aw   = (const float*)d_in[18];
  const float* Ab   = (const float*)d_in[19];
  const float* skip = (const float*)d_in[20];
  const float* ln_g = (const float*)d_in[21];
  const float* ln_b = (const float*)d_in[22];
  const float* Wout = (const float*)d_in[23];
  const float* b_out= (const float*)d_in[24];

  // ---- workspace (~180 MB) ----
  float* f = (float*)d_ws;
  unsigned short* hsP = (unsigned short*)f;              // 3 x 2NM ushorts  [0,3NM)
  float* qb3 = f + 3 * NM;                               // 3 x NM fp32      [3NM,6NM)
  unsigned short* km = (unsigned short*)(f + 6 * NM);    // 4 x KMU ushorts  [6NM,10NM)
  unsigned short* wprep = (unsigned short*)(f + 10 * NM);// 2 x PLANEU ushorts
  float* fb = (float*)(wprep + 2 * PLANEU);              // 16 x 512
  int* ib = (int*)(fb + 8192);
  int* cnt  = ib;
  int* rp   = ib + 4 * N_NODES;
  int* cur  = rp + 4 * (N_NODES + 1);
  int* srcl = cur + 4 * N_NODES;
  unsigned short* gp = (unsigned short*)d_out;           // 3 x 2NM ushorts scratch

  // prep (weights, x planes, CSR) — rebuilt every call
  prep_plain<<<dim3(32, 30), 256, 0, stream>>>(Win, Qw, Aw, Wout, wprep, wprep + PLANEU);
  fuse_kernel<<<dim3(8, 16, 2), 256, 0, stream>>>(Kw, Kb, Vw, Vb, Arel, Mrel,
                                                  wprep, wprep + PLANEU, fb);
  split_x<<<3 * NM / 2048, 256, 0, stream>>>(x0, x1, x2, gp);
  zero_cnt_kernel<<<4 * N_NODES / 256, 256, 0, stream>>>(cnt);
  count_kernel<<<4 * E_EDGES / 256, 256, 0, stream>>>(ei[0], ei[1], ei[2], ei[3], cnt);
  scan_kernel<<<4, 256, 0, stream>>>(cnt, rp, cur);
  fill_kernel<<<4 * E_EDGES / 256, 256, 0, stream>>>(ei[0], ei[1], ei[2], ei[3], cur, srcl);

  // input projections: x planes -> hs planes
  gemm3<1><<<dim3(256, 12), 256, 0, stream>>>(gp, wprep, 0, b_in, nullptr, hsP);

  for (int l = 0; l < 4; l++) {
    gemm_layer<<<dim3(256, 44), 256, 0, stream>>>(l, wprep, hsP, Qb, fb, qb3, km);
    attn_layer<<<3 * 4096, 256, 0, stream>>>(l, qb3, km, Prel, rp, srcl, gp);
    gemm3<0><<<dim3(256, 12), 256, 0, stream>>>(gp, wprep, 15 + l * 3, Ab + l * 3 * 256,
                                                qb3, nullptr);
    ln_layer<<<3 * N_NODES, 256, 0, stream>>>(l, qb3, hsP, skip, ln_g, ln_b);
  }

  // output projections into d_out (fp32)
  gemm3<0><<<dim3(256, 12), 256, 0, stream>>>(hsP, wprep, 27, b_out, (float*)d_out, nullptr);
}